// Round 8
// baseline (267.970 us; speedup 1.0000x reference)
//
#include <hip/hip_runtime.h>

// ---------------------------------------------------------------------------
// CustomMultiHeadAttentionStoich: fused MHA with RoPE + frac-difference bias.
// B=2 T=2048 D_MODEL=1024 H=16 hd=64. All matmuls via mfma_f32_16x16x32_bf16.
//
// Verified gfx950 fragment layouts (learn_hip m89/m91, rounds 1-7 pass):
//   A-frag : lane holds A[m=lane&15][k=(lane>>4)*8 + j], j=0..7  (8 bf16, 16B)
//   B-frag : lane holds B[k=(lane>>4)*8 + j][n=lane&15]
//   C/D    : lane holds D[row=(lane>>4)*4 + r][col=lane&15], r=0..3 (4 f32)
//
// Round-8 changes:
//  * k_attn: exact r5 version restored (77.5 us measured; r6/r7 variants
//    regressed to ~80-81).
//  * k_gemm_qkv: A staged DIRECTLY from f32 inputs (float4 loads -> cvt ->
//    ds_write_b128 into stride-72 sA, conflict-free; 1-iter register
//    pipeline). Xb bf16 intermediate + prep convert zone DELETED (-50 MB
//    round-trip, prep shrinks 7424 -> 1280 blocks).
//  * k_gemm_out / launcher structure unchanged (r7).
// ---------------------------------------------------------------------------

typedef unsigned short u16;
typedef __bf16 bf8v __attribute__((ext_vector_type(8)));
typedef __bf16 bf4v __attribute__((ext_vector_type(4)));
typedef float f32x4 __attribute__((ext_vector_type(4)));

#define D_MODEL 1024
#define T_SEQ   2048
#define NHEAD   16
#define HDIM    64
#define BATCH   2
#define M_TOT   (BATCH * T_SEQ) /* 4096 */
#define LOG2E   1.4426950408889634f

__device__ __forceinline__ void gl2lds16(const u16* g, u16* l) {
  __builtin_amdgcn_global_load_lds(
      (__attribute__((address_space(1))) void*)g,
      (__attribute__((address_space(3))) void*)l, 16, 0, 0);
}

// ---------------------------------------------------------------------------
// k_prep: W^T transpose + RoPE table in ONE launch (convert zone removed).
//   blocks [0,1024)    : W^T bf16 transpose of Wq/Wk/Wv/Wo into WtB
//   blocks [1024,1280) : RoPE cos/sin table
__global__ __launch_bounds__(256) void k_prep(
    const float* __restrict__ Wq, const float* __restrict__ Wk,
    const float* __restrict__ Wv, const float* __restrict__ Wo,
    u16* __restrict__ WtB, float* __restrict__ ct, float* __restrict__ st) {
  __shared__ float tile[64 * 65];
  int bx = blockIdx.x, tid = threadIdx.x;
  if (bx < 1024) { // ---- W transpose zone (64x64 tiles, stride 65)
    int z = bx >> 8, rem = bx & 255;
    int k0 = (rem >> 4) * 64, n0 = (rem & 15) * 64;
    const float* W = (z == 0) ? Wq : (z == 1) ? Wk : (z == 2) ? Wv : Wo;
    u16* Wt = WtB + (size_t)z * (D_MODEL * D_MODEL);
#pragma unroll
    for (int i = 0; i < 16; i++) {
      int idx = tid + i * 256;
      int r = idx >> 6, c = idx & 63;
      tile[c * 65 + r] = W[(size_t)(k0 + r) * D_MODEL + n0 + c];
    }
    __syncthreads();
#pragma unroll
    for (int i = 0; i < 16; i++) {
      int idx = tid + i * 256;
      int r = idx >> 6, c = idx & 63;
      ((__bf16*)Wt)[(size_t)(n0 + r) * D_MODEL + k0 + c] = (__bf16)tile[r * 65 + c];
    }
  } else { // ---- RoPE table zone: angle(t,d) = t / 10000^(d/32)
    int idx = (bx - 1024) * 256 + tid; // = t*32 + d
    int t = idx >> 5, d = idx & 31;
    float ang = (float)t * powf(10000.0f, -(float)d * (1.0f / 32.0f));
    ct[idx] = cosf(ang);
    st[idx] = sinf(ang);
  }
}

// ---------------------------------------------------------------------------
// QKV projection, grid (8, 32, 3). A read DIRECTLY from f32 input (float4 ->
// cvt -> ds_write_b128, stride-72 sA, register-pipelined one iter ahead);
// B (W^T bf16) staged via global_load_lds DMA (r7 path). BK=64.
// z<2 -> RoPE fused; z==0 prescales Q by 0.125*log2e. z==2 writes projected V
// DIRECTLY TRANSPOSED into Vb[b][h][d][t].
__global__ __launch_bounds__(256) void k_gemm_qkv(
    const float* __restrict__ qx, const float* __restrict__ kx,
    const float* __restrict__ vx, const u16* __restrict__ WtB,
    const float* __restrict__ bq, const float* __restrict__ bk,
    const float* __restrict__ bv, const float* __restrict__ ctab,
    const float* __restrict__ stab, u16* __restrict__ OutB,
    u16* __restrict__ Vb) {
  __shared__ __align__(16) u16 sA[128 * 72]; // [row][64 cols], stride 72
  __shared__ __align__(16) u16 sB[128 * 64]; // linear, 2 stride-32 planes (DMA)
  const int K = D_MODEL;
  int z = blockIdx.z;
  const float* Xf = (z == 0) ? qx : (z == 1) ? kx : vx;
  const u16* Bt = WtB + (size_t)z * (D_MODEL * D_MODEL);
  const float* bias = (z == 0) ? bq : (z == 1) ? bk : bv;
  u16* Out = OutB + (size_t)z * (M_TOT * D_MODEL);
  int m0 = blockIdx.y * 128, n0 = blockIdx.x * 128;

  int tid = threadIdx.x, lane = tid & 63, wave = tid >> 6;
  int l15 = lane & 15, quad = lane >> 4;
  int wm = (wave >> 1) * 64, wn = (wave & 1) * 64;

  // A staging map: thread covers rows r0 and r0+64, cols q4*16..q4*16+15
  int r0 = tid >> 2, q4 = tid & 3;
  const float* Ag0 = Xf + (size_t)(m0 + r0) * K + q4 * 16;
  const float* Ag1 = Ag0 + (size_t)64 * K;
  u16* wA0 = sA + r0 * 72 + q4 * 16;
  u16* wA1 = wA0 + 64 * 72;

  // B staging (DMA): rows r0 / r0+64, 8-elem chunk (tid&3)*8
  int pcol0 = (tid & 3) * 8;
  const u16* B0 = Bt + (size_t)(n0 + r0) * K + pcol0;
  const u16* B1 = B0 + (size_t)64 * K;
  u16* dB0 = sB + wave * 512; // wave-uniform; lane deposits at +lane*16B
  u16* dB1 = sB + 2048 + wave * 512;

  float4 va0[4], va1[4];
  auto loadA = [&](int k0) {
#pragma unroll
    for (int c = 0; c < 4; c++) {
      va0[c] = *(const float4*)(Ag0 + k0 + c * 4);
      va1[c] = *(const float4*)(Ag1 + k0 + c * 4);
    }
  };
  auto cvst = [&](u16* dst, const float4& a, const float4& b) {
    bf8v t;
    t[0] = (__bf16)a.x; t[1] = (__bf16)a.y; t[2] = (__bf16)a.z; t[3] = (__bf16)a.w;
    t[4] = (__bf16)b.x; t[5] = (__bf16)b.y; t[6] = (__bf16)b.z; t[7] = (__bf16)b.w;
    *(bf8v*)dst = t;
  };

  f32x4 acc[4][4] = {};
  loadA(0);
  for (int k0 = 0; k0 < K; k0 += 64) {
    __syncthreads(); // previous iter's frag reads done
    cvst(wA0, va0[0], va0[1]);
    cvst(wA0 + 8, va0[2], va0[3]);
    cvst(wA1, va1[0], va1[1]);
    cvst(wA1 + 8, va1[2], va1[3]);
    gl2lds16(B0 + k0, dB0);
    gl2lds16(B0 + k0 + 32, dB0 + 4096); // plane1
    gl2lds16(B1 + k0, dB1);
    gl2lds16(B1 + k0 + 32, dB1 + 4096);
    __syncthreads(); // drains DMA (vmcnt) + ds_writes (lgkm) -> tile visible
    if (k0 + 64 < K) loadA(k0 + 64); // next A loads fly under the MFMAs
#pragma unroll
    for (int kh = 0; kh < 2; kh++) {
      bf8v af[4], bf[4];
#pragma unroll
      for (int i = 0; i < 4; i++)
        af[i] = *(const bf8v*)(sA + (wm + i * 16 + l15) * 72 + kh * 32 + quad * 8);
#pragma unroll
      for (int i = 0; i < 4; i++)
        bf[i] = *(const bf8v*)(sB + kh * 4096 + (wn + i * 16 + l15) * 32 + quad * 8);
#pragma unroll
      for (int mi = 0; mi < 4; mi++)
#pragma unroll
        for (int ni = 0; ni < 4; ni++)
          acc[mi][ni] = __builtin_amdgcn_mfma_f32_16x16x32_bf16(
              af[mi], bf[ni], acc[mi][ni], 0, 0, 0);
    }
  }

  float bvv[4];
#pragma unroll
  for (int ni = 0; ni < 4; ni++) bvv[ni] = bias[n0 + wn + ni * 16 + l15];

  if (z < 2) { // Q/K: RoPE fused; Q also prescaled 0.125*log2e
    float qs = (z == 0) ? 0.125f * LOG2E : 1.0f;
#pragma unroll
    for (int mi = 0; mi < 4; mi++) {
#pragma unroll
      for (int r = 0; r < 4; r++) {
        int m = m0 + wm + mi * 16 + quad * 4 + r; // global row = b*T + t
        size_t ro = (size_t)m * D_MODEL + n0 + wn;
        int tl = m & (T_SEQ - 1);
#pragma unroll
        for (int ni = 0; ni < 2; ni++) {
          int d = ni * 16 + l15; // < 32; pair (d, d+32) in regs ni, ni+2
          float c = ctab[tl * 32 + d], s = stab[tl * 32 + d];
          float xl = acc[mi][ni][r] + bvv[ni];
          float xr = acc[mi][ni + 2][r] + bvv[ni + 2];
          ((__bf16*)Out)[ro + d] = (__bf16)((xl * c - xr * s) * qs);
          ((__bf16*)Out)[ro + d + 32] = (__bf16)((xl * s + xr * c) * qs);
        }
      }
    }
  } else { // V: write transposed Vb[b][h][d][t] (wave's 64 cols = one head)
    int hh = (n0 + wn) >> 6;
    int mbase = m0 + wm;
    int bb = mbase >> 11; // tile never crosses batch (2048 % 128 == 0)
    int tbase = mbase & (T_SEQ - 1);
    u16* Vw = Vb + (size_t)(bb * NHEAD + hh) * HDIM * T_SEQ;
#pragma unroll
    for (int mi = 0; mi < 4; mi++)
#pragma unroll
      for (int r = 0; r < 4; r++) {
        int t = tbase + mi * 16 + quad * 4 + r;
#pragma unroll
        for (int ni = 0; ni < 4; ni++) {
          int d = ni * 16 + l15;
          ((__bf16*)Vw)[(size_t)d * T_SEQ + t] = (__bf16)(acc[mi][ni][r] + bvv[ni]);
        }
      }
  }
}

// Output projection: ctx bf16 @ Wo^T + bo -> f32 d_out. 64x64 tiles, grid
// (16, 64) = 1024 blocks = 4 blocks/CU (LDS 16 KB). Wave-tile 32x32, BK=64.
__global__ __launch_bounds__(256) void k_gemm_out(
    const u16* __restrict__ ctx, const u16* __restrict__ Wot,
    const float* __restrict__ bo, float* __restrict__ Cout) {
  __shared__ __align__(16) u16 sA[64 * 64];
  __shared__ __align__(16) u16 sB[64 * 64];
  const int K = D_MODEL;
  int m0 = blockIdx.y * 64, n0 = blockIdx.x * 64;
  int tid = threadIdx.x, lane = tid & 63, wave = tid >> 6;
  int l15 = lane & 15, quad = lane >> 4;
  int wm = (wave >> 1) * 32, wn = (wave & 1) * 32;
  int r0 = tid >> 2, pcol0 = (tid & 3) * 8;
  const u16* A0 = ctx + (size_t)(m0 + r0) * K + pcol0;
  const u16* B0 = Wot + (size_t)(n0 + r0) * K + pcol0;
  u16* dA = sA + wave * 512; // one call = one full 64x32 plane (256 thr)
  u16* dB = sB + wave * 512;
  f32x4 acc[2][2] = {};
  for (int k0 = 0; k0 < K; k0 += 64) {
    __syncthreads(); // previous iter's frag reads done
    gl2lds16(A0 + k0, dA);
    gl2lds16(A0 + k0 + 32, dA + 2048); // plane1
    gl2lds16(B0 + k0, dB);
    gl2lds16(B0 + k0 + 32, dB + 2048);
    __syncthreads(); // barrier drain -> LDS data visible
#pragma unroll
    for (int kh = 0; kh < 2; kh++) {
      bf8v af[2], bf[2];
#pragma unroll
      for (int i = 0; i < 2; i++)
        af[i] = *(const bf8v*)(sA + kh * 2048 + (wm + i * 16 + l15) * 32 + quad * 8);
#pragma unroll
      for (int i = 0; i < 2; i++)
        bf[i] = *(const bf8v*)(sB + kh * 2048 + (wn + i * 16 + l15) * 32 + quad * 8);
#pragma unroll
      for (int mi = 0; mi < 2; mi++)
#pragma unroll
        for (int ni = 0; ni < 2; ni++)
          acc[mi][ni] = __builtin_amdgcn_mfma_f32_16x16x32_bf16(
              af[mi], bf[ni], acc[mi][ni], 0, 0, 0);
    }
  }
  float bvv[2];
#pragma unroll
  for (int ni = 0; ni < 2; ni++) bvv[ni] = bo[n0 + wn + ni * 16 + l15];
#pragma unroll
  for (int mi = 0; mi < 2; mi++)
#pragma unroll
    for (int r = 0; r < 4; r++) {
      size_t ro = (size_t)(m0 + wm + mi * 16 + quad * 4 + r) * D_MODEL + n0 + wn;
#pragma unroll
      for (int ni = 0; ni < 2; ni++)
        Cout[ro + ni * 16 + l15] = acc[mi][ni][r] + bvv[ni];
    }
}

// ---------------------------------------------------------------------------
// Flash attention (exact r5 version, 77.5 us): grid (T/128, B*H), 256 thr
// (4 waves x 32q). K/V double-buffered in LDS via global_load_lds DMA; ONE
// __syncthreads per tile. XOR-chunk swizzle (pc = gc ^ (row&7)). S^T = K@Q^T
// -> per-lane softmax, no max-subtraction, exp2-native. Per-g P round-trip:
// g1's exp VALU issues under g0's PV MFMAs.
__global__ __launch_bounds__(256) void k_attn(
    const u16* __restrict__ Qr, const u16* __restrict__ Kr,
    const u16* __restrict__ Vb, const float* __restrict__ frac,
    const float* __restrict__ alpha_pos, const float* __restrict__ alpha_neg,
    u16* __restrict__ ctx) {
  __shared__ __align__(16) u16 kT[2][64 * 64]; // swizzled [key][d], no pad
  __shared__ __align__(16) u16 vT[2][64 * 64]; // swizzled [d][key], no pad
  __shared__ __align__(16) u16 pT[4][2][16 * 72]; // per-wave per-g [q][key]
  int bh = blockIdx.y, b = bh >> 4, h = bh & 15;
  int q0 = blockIdx.x * 128;
  int tid = threadIdx.x, wave = tid >> 6, lane = tid & 63;
  int l15 = lane & 15, quad = lane >> 4;

  const u16* Kh = Kr + (size_t)b * T_SEQ * D_MODEL + h * HDIM;
  const u16* Vh = Vb + (size_t)bh * HDIM * T_SEQ;
  const float* fb = frac + b * T_SEQ;

  // Q B-frags (B[k=d][n=q] = Q[q][d]): lane holds Q[q=l15][d=quad*8+j]
  bf8v qf[2][2];
  float fq[2];
#pragma unroll
  for (int g = 0; g < 2; g++) {
    int qrow = q0 + wave * 32 + g * 16 + l15;
    const u16* qbase =
        Qr + (size_t)(b * T_SEQ + qrow) * D_MODEL + h * HDIM + quad * 8;
    qf[g][0] = *(const bf8v*)qbase;
    qf[g][1] = *(const bf8v*)(qbase + 32);
    fq[g] = fb[qrow]; // S^T col = q = l15
  }
  float ap = alpha_pos[h] * LOG2E, an = alpha_neg[h] * LOG2E;
  bf8v onesv;
#pragma unroll
  for (int j = 0; j < 8; j++) onesv[j] = (__bf16)1.0f;
  f32x4 o[2][4] = {};
  f32x4 o_l[2] = {};
  u16* pw = &pT[wave][0][0];

  // DMA staging map: physical chunk p = j*256 + wave*64 + lane;
  // row = p>>3, pc = p&7; fetch global chunk gc = pc ^ (row&7).
  int p0 = tid, p1 = 256 + tid;
  int kr0 = p0 >> 3, gc0 = (p0 & 7) ^ (kr0 & 7);
  int kr1 = p1 >> 3, gc1 = (p1 & 7) ^ (kr1 & 7);
  const u16* kg0 = Kh + (size_t)kr0 * D_MODEL + gc0 * 8;
  const u16* kg1 = Kh + (size_t)kr1 * D_MODEL + gc1 * 8;
  const u16* vg0 = Vh + (size_t)kr0 * T_SEQ + gc0 * 8; // row = d here
  const u16* vg1 = Vh + (size_t)kr1 * T_SEQ + gc1 * 8;
  int woff = wave * 512; // wave-uniform LDS dest (elems); lane -> +lane*8

  auto stage = [&](int buf, int kbase) {
    gl2lds16(kg0 + (size_t)kbase * D_MODEL, kT[buf] + woff);
    gl2lds16(kg1 + (size_t)kbase * D_MODEL, kT[buf] + 2048 + woff);
    gl2lds16(vg0 + kbase, vT[buf] + woff);
    gl2lds16(vg1 + kbase, vT[buf] + 2048 + woff);
  };

  stage(0, 0);
  __syncthreads();

  for (int kt = 0; kt < T_SEQ / 64; kt++) {
    int kbase = kt * 64;
    int buf = kt & 1;
    if (kt + 1 < T_SEQ / 64) stage(buf ^ 1, kbase + 64);

    // K A-frags via swizzle: row k = nt*16+l15; chunk gc -> pc = gc^(k&7)
    bf8v kf0[4], kf1[4];
    int x0 = (quad ^ (l15 & 7)) * 8; // pc for gc=quad; gc=quad+4 -> ^32 elems
#pragma unroll
    for (int nt = 0; nt < 4; nt++) {
      const u16* rb = kT[buf] + ((nt * 16 + l15) << 6);
      kf0[nt] = *(const bf8v*)(rb + x0);
      kf1[nt] = *(const bf8v*)(rb + (x0 ^ 32));
    }
    // V B-frags: row d = dt*16+l15; key-chunks gc = kc*4+quad
    bf8v vf[2][4];
#pragma unroll
    for (int dt = 0; dt < 4; dt++) {
      const u16* rb = vT[buf] + ((dt * 16 + l15) << 6);
      vf[0][dt] = *(const bf8v*)(rb + x0);
      vf[1][dt] = *(const bf8v*)(rb + (x0 ^ 32));
    }
    f32x4 fk4[4];
#pragma unroll
    for (int nt = 0; nt < 4; nt++)
      fk4[nt] = *(const f32x4*)(fb + kbase + nt * 16 + quad * 4);

#pragma unroll
    for (int g = 0; g < 2; g++) {
      float fqg = fq[g];
      u16* pwg = pw + g * (16 * 72);
#pragma unroll
      for (int nt = 0; nt < 4; nt++) {
        // S^T tile: D[row=key=nt*16+quad*4+r][col=q=l15], log2 domain
        f32x4 s = {};
        s = __builtin_amdgcn_mfma_f32_16x16x32_bf16(kf0[nt], qf[g][0], s, 0, 0, 0);
        s = __builtin_amdgcn_mfma_f32_16x16x32_bf16(kf1[nt], qf[g][1], s, 0, 0, 0);
        bf4v pk;
#pragma unroll
        for (int r = 0; r < 4; r++) {
          float dd = fk4[nt][r] - fqg;
          float sel = (dd >= 0.0f) ? ap : an;
          pk[r] = (__bf16)__builtin_amdgcn_exp2f(fmaf(dd, sel, s[r]));
        }
        // P[q=l15][key = nt*16 + quad*4 + r] -> one b64 write
        *(bf4v*)(pwg + l15 * 72 + nt * 16 + quad * 4) = pk;
      }
      asm volatile("s_waitcnt lgkmcnt(0)" ::: "memory"); // P visible to own wave
      // O_g += P_g @ V ; l_g += P_g @ ones. Drains while next g's score
      // VALU issues (separate pipes, same wave).
#pragma unroll
      for (int kc = 0; kc < 2; kc++) {
        bf8v pf = *(const bf8v*)(pwg + l15 * 72 + kc * 32 + quad * 8);
        o_l[g] = __builtin_amdgcn_mfma_f32_16x16x32_bf16(pf, onesv, o_l[g], 0, 0, 0);
#pragma unroll
        for (int dt = 0; dt < 4; dt++)
          o[g][dt] = __builtin_amdgcn_mfma_f32_16x16x32_bf16(pf, vf[kc][dt],
                                                             o[g][dt], 0, 0, 0);
      }
    }
    __syncthreads(); // drains this iter's DMA (vmcnt) + frees cur buf
  }

  // epilogue: l sits in o_l C-layout rows (same rows as o)
#pragma unroll
  for (int g = 0; g < 2; g++) {
#pragma unroll
    for (int r = 0; r < 4; r++) {
      float linv = 1.0f / o_l[g][r];
      int qg = q0 + wave * 32 + g * 16 + quad * 4 + r;
      __bf16* orow = (__bf16*)(ctx + (size_t)(b * T_SEQ + qg) * D_MODEL + h * HDIM);
#pragma unroll
      for (int dt = 0; dt < 4; dt++)
        orow[dt * 16 + l15] = (__bf16)(o[g][dt][r] * linv);
    }
  }
}

// ---------------------------------------------------------------------------
extern "C" void kernel_launch(void* const* d_in, const int* in_sizes, int n_in,
                              void* d_out, int out_size, void* d_ws,
                              size_t ws_size, hipStream_t stream) {
  const float* q = (const float*)d_in[0];
  const float* k = (const float*)d_in[1];
  const float* v = (const float*)d_in[2];
  const float* frac = (const float*)d_in[3];
  const float* Wq = (const float*)d_in[4];
  const float* Wk = (const float*)d_in[5];
  const float* Wv = (const float*)d_in[6];
  const float* Wo = (const float*)d_in[7];
  const float* bq = (const float*)d_in[8];
  const float* bk = (const float*)d_in[9];
  const float* bv = (const float*)d_in[10];
  const float* bo = (const float*)d_in[11];
  const float* alpha_pos = (const float*)d_in[12];
  const float* alpha_neg = (const float*)d_in[13];

  char* ws = (char*)d_ws;
  u16* Wt = (u16*)(ws + 25165824);
  u16* Qr = (u16*)(ws + 33554432);
  u16* Kr = (u16*)(ws + 41943040);
  u16* Vtmp = (u16*)(ws + 50331648); // holds ctx
  u16* Vb = (u16*)(ws + 58720256);
  float* ctab = (float*)(ws + 67108864);
  float* stab = (float*)(ws + 67371008);
  u16* ctx = Vtmp;
  u16* QKVout = Qr; // Qr,Kr contiguous; z==2 writes Vb directly

  k_prep<<<dim3(1280), 256, 0, stream>>>(Wq, Wk, Wv, Wo, Wt, ctab, stab);
  k_gemm_qkv<<<dim3(8, 32, 3), 256, 0, stream>>>(q, k, v, Wt, bq, bk, bv, ctab,
                                                 stab, QKVout, Vb);
  k_attn<<<dim3(16, 32), 256, 0, stream>>>(Qr, Kr, Vb, frac, alpha_pos,
                                           alpha_neg, ctx);
  k_gemm_out<<<dim3(16, 64), 256, 0, stream>>>(ctx, Wt + 3 * 1048576, bo,
                                               (float*)d_out);
}